// Round 3
// baseline (1019.221 us; speedup 1.0000x reference)
//
#include <hip/hip_runtime.h>
#include <cstdint>
#include <cstddef>

#define TOKS 4096
#define HID  1024
#define FFN  2816
#define NE   8
#define CAP  4096   // per-expert token capacity (worst case)

using floatx4 = __attribute__((ext_vector_type(4))) float;
using bf16x8  = __attribute__((ext_vector_type(8))) short;

__device__ __forceinline__ unsigned short f2bf(float f) {
    union { float f; unsigned int u; } v; v.f = f;
    unsigned int r = v.u + 0x7FFFu + ((v.u >> 16) & 1u);   // RNE
    return (unsigned short)(r >> 16);
}

// async global->LDS, 16B per lane; LDS dest is wave-uniform base + lane*16
#define GLOAD16(g, l) __builtin_amdgcn_global_load_lds( \
    (__attribute__((address_space(1))) void*)(g),        \
    (__attribute__((address_space(3))) void*)(l), 16, 0, 0)

// ---------------------------------------------------------------- RMSNorm
__global__ __launch_bounds__(256) void k_rmsnorm(const float* __restrict__ x,
                                                 const float* __restrict__ g,
                                                 unsigned short* __restrict__ xn)
{
    const int t = blockIdx.x;
    const int tid = threadIdx.x;
    const float4 v = *(const float4*)(x + (size_t)t*HID + tid*4);
    float ss = v.x*v.x + v.y*v.y + v.z*v.z + v.w*v.w;
    #pragma unroll
    for (int s = 32; s; s >>= 1) ss += __shfl_xor(ss, s, 64);
    __shared__ float red[4];
    if ((tid & 63) == 0) red[tid >> 6] = ss;
    __syncthreads();
    const float tot = red[0] + red[1] + red[2] + red[3];
    const float sc = rsqrtf(tot * (1.0f/HID) + 1e-5f);
    const float4 gw = *(const float4*)(g + tid*4);
    ushort4 o;
    o.x = f2bf(v.x*sc*gw.x); o.y = f2bf(v.y*sc*gw.y);
    o.z = f2bf(v.z*sc*gw.z); o.w = f2bf(v.w*sc*gw.w);
    *(ushort4*)(xn + (size_t)t*HID + tid*4) = o;
}

// ---------------------------------------------------------------- Router (fp32, one wave per token)
__global__ __launch_bounds__(256) void k_router(const float* __restrict__ x,
                                                const float* __restrict__ g,
                                                const float* __restrict__ rw,  // [HID][NE]
                                                int* __restrict__ cnt,
                                                int* __restrict__ ids,
                                                float* __restrict__ gates)
{
    const int wid = threadIdx.x >> 6, lane = threadIdx.x & 63;
    const int t = blockIdx.x*4 + wid;
    const float* xr = x + (size_t)t*HID;
    float ss = 0.f;
    float acc[NE];
    #pragma unroll
    for (int e = 0; e < NE; ++e) acc[e] = 0.f;
    for (int h = lane; h < HID; h += 64) {
        const float xv = xr[h];
        ss += xv*xv;
        const float xg = xv * g[h];
        const float4 r0 = *(const float4*)(rw + h*NE);
        const float4 r1 = *(const float4*)(rw + h*NE + 4);
        acc[0] += xg*r0.x; acc[1] += xg*r0.y; acc[2] += xg*r0.z; acc[3] += xg*r0.w;
        acc[4] += xg*r1.x; acc[5] += xg*r1.y; acc[6] += xg*r1.z; acc[7] += xg*r1.w;
    }
    #pragma unroll
    for (int s = 32; s; s >>= 1) {
        ss += __shfl_xor(ss, s, 64);
        #pragma unroll
        for (int e = 0; e < NE; ++e) acc[e] += __shfl_xor(acc[e], s, 64);
    }
    if (lane == 0) {
        const float sc = rsqrtf(ss * (1.0f/HID) + 1e-5f);
        float p[NE];
        float m = -1e30f;
        #pragma unroll
        for (int e = 0; e < NE; ++e) { p[e] = acc[e]*sc; if (p[e] > m) m = p[e]; }
        float sum = 0.f;
        #pragma unroll
        for (int e = 0; e < NE; ++e) { p[e] = __expf(p[e] - m); sum += p[e]; }
        const float inv = 1.f / sum;
        int i1 = 0; float p1 = p[0];
        #pragma unroll
        for (int e = 1; e < NE; ++e) if (p[e] > p1) { p1 = p[e]; i1 = e; }
        int i2 = -1; float p2 = -1.f;
        #pragma unroll
        for (int e = 0; e < NE; ++e) if (e != i1 && p[e] > p2) { p2 = p[e]; i2 = e; }
        int s0 = atomicAdd(cnt + i1, 1);
        ids[i1*CAP + s0] = t; gates[i1*CAP + s0] = p1*inv;
        int s1 = atomicAdd(cnt + i2, 1);
        ids[i2*CAP + s1] = t; gates[i2*CAP + s1] = p2*inv;
    }
}

// ---------------------------------------------------------------- prefix scan (8 experts)
__global__ void k_scan(const int* __restrict__ cnt, int* __restrict__ off)
{
    if (threadIdx.x == 0) {
        int s = 0;
        for (int e = 0; e < NE; ++e) { off[e] = s; s += cnt[e]; }
        off[NE] = s;
    }
}

// ---------------------------------------------------------------- fp32 -> bf16 transpose ([R][C] -> [C][R])
__global__ __launch_bounds__(256) void k_convtrans(const float* __restrict__ w1,
                                                   const float* __restrict__ w3,
                                                   const float* __restrict__ w2,
                                                   unsigned short* __restrict__ w1t,
                                                   unsigned short* __restrict__ w3t,
                                                   unsigned short* __restrict__ w2t)
{
    const int which = blockIdx.y;
    const int e = blockIdx.z;
    const float* src; unsigned short* dst; int R, C;
    if (which == 0)      { src = w1; dst = w1t; R = HID; C = FFN; }
    else if (which == 1) { src = w3; dst = w3t; R = HID; C = FFN; }
    else                 { src = w2; dst = w2t; R = FFN; C = HID; }
    src += (size_t)e * R * C;
    dst += (size_t)e * R * C;
    const int tiles_r = R >> 6;
    const int tr = blockIdx.x % tiles_r;
    const int tc = blockIdx.x / tiles_r;
    const int r0 = tr << 6, c0 = tc << 6;
    __shared__ unsigned short lds[64*66];
    const int tid = threadIdx.x;
    #pragma unroll
    for (int it = 0; it < 4; ++it) {
        const int id = it*256 + tid;
        const int r = id >> 4;
        const int c4 = (id & 15) << 2;
        const float4 v = *(const float4*)(src + (size_t)(r0 + r)*C + c0 + c4);
        lds[r*66 + c4 + 0] = f2bf(v.x);
        lds[r*66 + c4 + 1] = f2bf(v.y);
        lds[r*66 + c4 + 2] = f2bf(v.z);
        lds[r*66 + c4 + 3] = f2bf(v.w);
    }
    __syncthreads();
    #pragma unroll
    for (int it = 0; it < 2; ++it) {
        const int id = it*256 + tid;
        const int cc = id >> 3;           // 0..63
        const int rv = (id & 7) << 3;     // 0..56
        bf16x8 o;
        #pragma unroll
        for (int j = 0; j < 8; ++j) o[j] = (short)lds[(rv + j)*66 + cc];
        *(bf16x8*)(dst + (size_t)(c0 + cc)*R + r0 + rv) = o;
    }
}

// ---------------------------------------------------------------- GEMM1: act = silu(Xg@w1) * (Xg@w3)
// Tile 128M x 64N x 128K. LDS 64 KB -> 2 blocks/CU. 8 K-iters.
__global__ __launch_bounds__(256, 2) void k_gemm1(
    const unsigned short* __restrict__ xn,
    const unsigned short* __restrict__ w1t,   // [E][F][H] bf16 (B^T)
    const unsigned short* __restrict__ w3t,
    const int* __restrict__ ids,
    const int* __restrict__ cnt,
    const int* __restrict__ off,
    unsigned short* __restrict__ act)         // [8192][F] bf16
{
    const int e = blockIdx.z;
    const int cn = cnt[e];
    const int m0 = blockIdx.x * 128;
    if (m0 >= cn) return;
    const int n0 = blockIdx.y * 64;
    const int base = off[e];

    __shared__ __align__(16) unsigned short sA [128*128];  // 32 KB
    __shared__ __align__(16) unsigned short sB1[64*128];   // 16 KB
    __shared__ __align__(16) unsigned short sB3[64*128];   // 16 KB

    const int tid  = threadIdx.x;
    const int wid  = tid >> 6;
    const int lane = tid & 63;
    const int lrow = lane >> 4;          // 0..3: row within 4-row staging group
    const int lchk = lane & 15;          // LDS chunk slot within row

    // staging pointers: LDS layout row*16 chunks, chunk c stored at slot c^(row&15)
    const unsigned short* aG[8];
    #pragma unroll
    for (int j = 0; j < 8; ++j) {
        const int row = (wid*8 + j)*4 + lrow;
        int rr = m0 + row; if (rr > cn - 1) rr = cn - 1;
        const int tok = ids[e*CAP + rr];
        const int c = lchk ^ (row & 15);
        aG[j] = xn + (size_t)tok*HID + c*8;
    }
    const unsigned short *b1G[4], *b3G[4];
    #pragma unroll
    for (int j = 0; j < 4; ++j) {
        const int row = (wid*4 + j)*4 + lrow;
        const int n = n0 + row;
        const int c = lchk ^ (row & 15);
        b1G[j] = w1t + ((size_t)e*FFN + n)*HID + c*8;
        b3G[j] = w3t + ((size_t)e*FFN + n)*HID + c*8;
    }

    floatx4 acc1[4][2], acc3[4][2];
    #pragma unroll
    for (int a = 0; a < 4; ++a)
      #pragma unroll
      for (int b = 0; b < 2; ++b) {
        acc1[a][b] = (floatx4){0.f,0.f,0.f,0.f};
        acc3[a][b] = (floatx4){0.f,0.f,0.f,0.f};
      }

    const int wm  = (wid >> 1) * 64;     // wave M offset
    const int wn  = (wid & 1) * 32;      // wave N offset
    const int r16 = lane & 15;
    const int q   = lane >> 4;

    for (int kt = 0; kt < HID; kt += 128) {
        __syncthreads();
        #pragma unroll
        for (int j = 0; j < 8; ++j) GLOAD16(aG[j] + kt, sA + (wid*8 + j)*512);
        #pragma unroll
        for (int j = 0; j < 4; ++j) {
            GLOAD16(b1G[j] + kt, sB1 + (wid*4 + j)*512);
            GLOAD16(b3G[j] + kt, sB3 + (wid*4 + j)*512);
        }
        __syncthreads();
        #pragma unroll
        for (int kk = 0; kk < 4; ++kk) {
            const int slot = (((kk*4 + q) ^ r16) << 3);
            bf16x8 a[4];
            #pragma unroll
            for (int mt = 0; mt < 4; ++mt)
                a[mt] = *(const bf16x8*)(sA + (wm + mt*16 + r16)*128 + slot);
            #pragma unroll
            for (int nt = 0; nt < 2; ++nt) {
                const bf16x8 b1 = *(const bf16x8*)(sB1 + (wn + nt*16 + r16)*128 + slot);
                const bf16x8 b3 = *(const bf16x8*)(sB3 + (wn + nt*16 + r16)*128 + slot);
                #pragma unroll
                for (int mt = 0; mt < 4; ++mt) {
                    acc1[mt][nt] = __builtin_amdgcn_mfma_f32_16x16x32_bf16(a[mt], b1, acc1[mt][nt], 0, 0, 0);
                    acc3[mt][nt] = __builtin_amdgcn_mfma_f32_16x16x32_bf16(a[mt], b3, acc3[mt][nt], 0, 0, 0);
                }
            }
        }
    }

    #pragma unroll
    for (int mt = 0; mt < 4; ++mt)
      #pragma unroll
      for (int i = 0; i < 4; ++i) {
        const int row = wm + mt*16 + q*4 + i;   // C/D: col=lane&15, row=(lane>>4)*4+reg
        if (m0 + row < cn) {
            unsigned short* rp = act + (size_t)(base + m0 + row)*FFN + n0 + wn + r16;
            #pragma unroll
            for (int nt = 0; nt < 2; ++nt) {
                const float h1 = acc1[mt][nt][i];
                const float h3 = acc3[mt][nt][i];
                rp[nt*16] = f2bf(h1 / (1.f + __expf(-h1)) * h3);
            }
        }
      }
}

// ---------------------------------------------------------------- GEMM2: out += gate * (act @ w2)
// Tile 128M x 64N x 128K. LDS 48 KB -> 3 blocks/CU. 22 K-iters.
__global__ __launch_bounds__(256, 3) void k_gemm2(
    const unsigned short* __restrict__ act,
    const unsigned short* __restrict__ w2t,   // [E][H][F] bf16 (B^T)
    const int* __restrict__ ids,
    const float* __restrict__ gates,
    const int* __restrict__ cnt,
    const int* __restrict__ off,
    float* __restrict__ out)
{
    const int e = blockIdx.z;
    const int cn = cnt[e];
    const int m0 = blockIdx.x * 128;
    if (m0 >= cn) return;
    const int n0 = blockIdx.y * 64;
    const int base = off[e];

    __shared__ __align__(16) unsigned short sA[128*128];   // 32 KB
    __shared__ __align__(16) unsigned short sB[64*128];    // 16 KB

    const int tid  = threadIdx.x;
    const int wid  = tid >> 6;
    const int lane = tid & 63;
    const int lrow = lane >> 4;
    const int lchk = lane & 15;

    const unsigned short* aG[8];
    #pragma unroll
    for (int j = 0; j < 8; ++j) {
        const int row = (wid*8 + j)*4 + lrow;
        int rr = m0 + row; if (rr > cn - 1) rr = cn - 1;
        const int c = lchk ^ (row & 15);
        aG[j] = act + (size_t)(base + rr)*FFN + c*8;
    }
    const unsigned short* bG[4];
    #pragma unroll
    for (int j = 0; j < 4; ++j) {
        const int row = (wid*4 + j)*4 + lrow;
        const int c = lchk ^ (row & 15);
        bG[j] = w2t + ((size_t)e*HID + n0 + row)*FFN + c*8;
    }

    floatx4 acc[4][2];
    #pragma unroll
    for (int a = 0; a < 4; ++a)
      #pragma unroll
      for (int b = 0; b < 2; ++b) acc[a][b] = (floatx4){0.f,0.f,0.f,0.f};

    const int wm  = (wid >> 1) * 64;
    const int wn  = (wid & 1) * 32;
    const int r16 = lane & 15;
    const int q   = lane >> 4;

    for (int kt = 0; kt < FFN; kt += 128) {
        __syncthreads();
        #pragma unroll
        for (int j = 0; j < 8; ++j) GLOAD16(aG[j] + kt, sA + (wid*8 + j)*512);
        #pragma unroll
        for (int j = 0; j < 4; ++j) GLOAD16(bG[j] + kt, sB + (wid*4 + j)*512);
        __syncthreads();
        #pragma unroll
        for (int kk = 0; kk < 4; ++kk) {
            const int slot = (((kk*4 + q) ^ r16) << 3);
            bf16x8 a[4];
            #pragma unroll
            for (int mt = 0; mt < 4; ++mt)
                a[mt] = *(const bf16x8*)(sA + (wm + mt*16 + r16)*128 + slot);
            #pragma unroll
            for (int nt = 0; nt < 2; ++nt) {
                const bf16x8 b = *(const bf16x8*)(sB + (wn + nt*16 + r16)*128 + slot);
                #pragma unroll
                for (int mt = 0; mt < 4; ++mt)
                    acc[mt][nt] = __builtin_amdgcn_mfma_f32_16x16x32_bf16(a[mt], b, acc[mt][nt], 0, 0, 0);
            }
        }
    }

    #pragma unroll
    for (int mt = 0; mt < 4; ++mt)
      #pragma unroll
      for (int i = 0; i < 4; ++i) {
        const int row = wm + mt*16 + q*4 + i;
        if (m0 + row < cn) {
            const int idx = e*CAP + m0 + row;
            const int tok = ids[idx];
            const float gg = gates[idx];
            float* op = out + (size_t)tok*HID + n0 + wn + r16;
            #pragma unroll
            for (int nt = 0; nt < 2; ++nt)
                atomicAdd(op + nt*16, gg * acc[mt][nt][i]);
        }
      }
}

// ---------------------------------------------------------------- launch
extern "C" void kernel_launch(void* const* d_in, const int* in_sizes, int n_in,
                              void* d_out, int out_size, void* d_ws, size_t ws_size,
                              hipStream_t stream)
{
    const float* hs  = (const float*)d_in[0];
    const float* lnw = (const float*)d_in[1];
    const float* rw  = (const float*)d_in[2];
    const float* w1  = (const float*)d_in[3];
    const float* w3  = (const float*)d_in[4];
    const float* w2  = (const float*)d_in[5];
    float* out = (float*)d_out;
    char* ws = (char*)d_ws;

    constexpr size_t WS_CNT   = 0;
    constexpr size_t WS_OFF   = 64;
    constexpr size_t WS_IDS   = 256;
    constexpr size_t WS_GATES = WS_IDS + sizeof(int)*NE*CAP;          // 131328
    constexpr size_t WS_XN    = 327680;
    constexpr size_t WS_W1T   = WS_XN  + (size_t)2*TOKS*HID;          // +8 MiB
    constexpr size_t WS_W3T   = WS_W1T + (size_t)2*NE*FFN*HID;        // +44 MiB each
    constexpr size_t WS_W2T   = WS_W3T + (size_t)2*NE*FFN*HID;
    constexpr size_t WS_ACT   = WS_W2T + (size_t)2*NE*FFN*HID;
    constexpr size_t WS_END   = WS_ACT + (size_t)2*2*TOKS*FFN;        // ~184.3 MiB total

    hipMemsetAsync(out, 0, sizeof(float)*(size_t)out_size, stream);
    if (ws_size < WS_END) return;   // visible failure mode: zero output
    hipMemsetAsync(ws, 0, 256, stream);

    int* cnt   = (int*)(ws + WS_CNT);
    int* off   = (int*)(ws + WS_OFF);
    int* ids   = (int*)(ws + WS_IDS);
    float* gts = (float*)(ws + WS_GATES);
    unsigned short* xn  = (unsigned short*)(ws + WS_XN);
    unsigned short* w1t = (unsigned short*)(ws + WS_W1T);
    unsigned short* w3t = (unsigned short*)(ws + WS_W3T);
    unsigned short* w2t = (unsigned short*)(ws + WS_W2T);
    unsigned short* act = (unsigned short*)(ws + WS_ACT);

    k_rmsnorm  <<<TOKS,            256, 0, stream>>>(hs, lnw, xn);
    k_router   <<<TOKS/4,          256, 0, stream>>>(hs, lnw, rw, cnt, ids, gts);
    k_scan     <<<1,               64,  0, stream>>>(cnt, off);
    k_convtrans<<<dim3(704,3,NE),  256, 0, stream>>>(w1, w3, w2, w1t, w3t, w2t);
    k_gemm1    <<<dim3(32,44,NE),  256, 0, stream>>>(xn, w1t, w3t, ids, cnt, off, act);
    k_gemm2    <<<dim3(32,16,NE),  256, 0, stream>>>(act, w2t, ids, gts, cnt, off, out);
}

// Round 4
// 756.808 us; speedup vs baseline: 1.3467x; 1.3467x over previous
//
#include <hip/hip_runtime.h>
#include <cstdint>
#include <cstddef>

#define TOKS 4096
#define HID  1024
#define FFN  2816
#define NE   8
#define CAP  4096   // per-expert token capacity (worst case)

using floatx4 = __attribute__((ext_vector_type(4))) float;
using bf16x8  = __attribute__((ext_vector_type(8))) short;

__device__ __forceinline__ unsigned short f2bf(float f) {
    union { float f; unsigned int u; } v; v.f = f;
    unsigned int r = v.u + 0x7FFFu + ((v.u >> 16) & 1u);   // RNE
    return (unsigned short)(r >> 16);
}

// async global->LDS, 16B per lane; LDS dest is wave-uniform base + lane*16
#define GLOAD16(g, l) __builtin_amdgcn_global_load_lds( \
    (__attribute__((address_space(1))) void*)(g),        \
    (__attribute__((address_space(3))) void*)(l), 16, 0, 0)

// ---------------------------------------------------------------- RMSNorm
__global__ __launch_bounds__(256) void k_rmsnorm(const float* __restrict__ x,
                                                 const float* __restrict__ g,
                                                 unsigned short* __restrict__ xn)
{
    const int t = blockIdx.x;
    const int tid = threadIdx.x;
    const float4 v = *(const float4*)(x + (size_t)t*HID + tid*4);
    float ss = v.x*v.x + v.y*v.y + v.z*v.z + v.w*v.w;
    #pragma unroll
    for (int s = 32; s; s >>= 1) ss += __shfl_xor(ss, s, 64);
    __shared__ float red[4];
    if ((tid & 63) == 0) red[tid >> 6] = ss;
    __syncthreads();
    const float tot = red[0] + red[1] + red[2] + red[3];
    const float sc = rsqrtf(tot * (1.0f/HID) + 1e-5f);
    const float4 gw = *(const float4*)(g + tid*4);
    ushort4 o;
    o.x = f2bf(v.x*sc*gw.x); o.y = f2bf(v.y*sc*gw.y);
    o.z = f2bf(v.z*sc*gw.z); o.w = f2bf(v.w*sc*gw.w);
    *(ushort4*)(xn + (size_t)t*HID + tid*4) = o;
}

// ---------------------------------------------------------------- Router (fp32, one wave per token)
__global__ __launch_bounds__(256) void k_router(const float* __restrict__ x,
                                                const float* __restrict__ g,
                                                const float* __restrict__ rw,  // [HID][NE]
                                                int* __restrict__ cnt,
                                                int* __restrict__ ids,
                                                float* __restrict__ gates)
{
    const int wid = threadIdx.x >> 6, lane = threadIdx.x & 63;
    const int t = blockIdx.x*4 + wid;
    const float* xr = x + (size_t)t*HID;
    float ss = 0.f;
    float acc[NE];
    #pragma unroll
    for (int e = 0; e < NE; ++e) acc[e] = 0.f;
    for (int h = lane; h < HID; h += 64) {
        const float xv = xr[h];
        ss += xv*xv;
        const float xg = xv * g[h];
        const float4 r0 = *(const float4*)(rw + h*NE);
        const float4 r1 = *(const float4*)(rw + h*NE + 4);
        acc[0] += xg*r0.x; acc[1] += xg*r0.y; acc[2] += xg*r0.z; acc[3] += xg*r0.w;
        acc[4] += xg*r1.x; acc[5] += xg*r1.y; acc[6] += xg*r1.z; acc[7] += xg*r1.w;
    }
    #pragma unroll
    for (int s = 32; s; s >>= 1) {
        ss += __shfl_xor(ss, s, 64);
        #pragma unroll
        for (int e = 0; e < NE; ++e) acc[e] += __shfl_xor(acc[e], s, 64);
    }
    if (lane == 0) {
        const float sc = rsqrtf(ss * (1.0f/HID) + 1e-5f);
        float p[NE];
        float m = -1e30f;
        #pragma unroll
        for (int e = 0; e < NE; ++e) { p[e] = acc[e]*sc; if (p[e] > m) m = p[e]; }
        float sum = 0.f;
        #pragma unroll
        for (int e = 0; e < NE; ++e) { p[e] = __expf(p[e] - m); sum += p[e]; }
        const float inv = 1.f / sum;
        int i1 = 0; float p1 = p[0];
        #pragma unroll
        for (int e = 1; e < NE; ++e) if (p[e] > p1) { p1 = p[e]; i1 = e; }
        int i2 = -1; float p2 = -1.f;
        #pragma unroll
        for (int e = 0; e < NE; ++e) if (e != i1 && p[e] > p2) { p2 = p[e]; i2 = e; }
        int s0 = atomicAdd(cnt + i1, 1);
        ids[i1*CAP + s0] = t; gates[i1*CAP + s0] = p1*inv;
        int s1 = atomicAdd(cnt + i2, 1);
        ids[i2*CAP + s1] = t; gates[i2*CAP + s1] = p2*inv;
    }
}

// ---------------------------------------------------------------- prefix scan (8 experts)
__global__ void k_scan(const int* __restrict__ cnt, int* __restrict__ off)
{
    if (threadIdx.x == 0) {
        int s = 0;
        for (int e = 0; e < NE; ++e) { off[e] = s; s += cnt[e]; }
        off[NE] = s;
    }
}

// ---------------------------------------------------------------- fp32 -> bf16 transpose ([R][C] -> [C][R])
__global__ __launch_bounds__(256) void k_convtrans(const float* __restrict__ w1,
                                                   const float* __restrict__ w3,
                                                   const float* __restrict__ w2,
                                                   unsigned short* __restrict__ w1t,
                                                   unsigned short* __restrict__ w3t,
                                                   unsigned short* __restrict__ w2t)
{
    const int which = blockIdx.y;
    const int e = blockIdx.z;
    const float* src; unsigned short* dst; int R, C;
    if (which == 0)      { src = w1; dst = w1t; R = HID; C = FFN; }
    else if (which == 1) { src = w3; dst = w3t; R = HID; C = FFN; }
    else                 { src = w2; dst = w2t; R = FFN; C = HID; }
    src += (size_t)e * R * C;
    dst += (size_t)e * R * C;
    const int tiles_r = R >> 6;
    const int tr = blockIdx.x % tiles_r;
    const int tc = blockIdx.x / tiles_r;
    const int r0 = tr << 6, c0 = tc << 6;
    __shared__ unsigned short lds[64*66];
    const int tid = threadIdx.x;
    #pragma unroll
    for (int it = 0; it < 4; ++it) {
        const int id = it*256 + tid;
        const int r = id >> 4;
        const int c4 = (id & 15) << 2;
        const float4 v = *(const float4*)(src + (size_t)(r0 + r)*C + c0 + c4);
        lds[r*66 + c4 + 0] = f2bf(v.x);
        lds[r*66 + c4 + 1] = f2bf(v.y);
        lds[r*66 + c4 + 2] = f2bf(v.z);
        lds[r*66 + c4 + 3] = f2bf(v.w);
    }
    __syncthreads();
    #pragma unroll
    for (int it = 0; it < 2; ++it) {
        const int id = it*256 + tid;
        const int cc = id >> 3;           // 0..63
        const int rv = (id & 7) << 3;     // 0..56
        bf16x8 o;
        #pragma unroll
        for (int j = 0; j < 8; ++j) o[j] = (short)lds[(rv + j)*66 + cc];
        *(bf16x8*)(dst + (size_t)(c0 + cc)*R + r0 + rv) = o;
    }
}

// ---------------------------------------------------------------- GEMM1: act = silu(Xg@w1) * (Xg@w3)
// Tile 128M x 64N x 64K. LDS 32 KB -> 4 blocks/CU. grid (n,m,e) for L2 reuse.
__global__ __launch_bounds__(256, 4) void k_gemm1(
    const unsigned short* __restrict__ xn,
    const unsigned short* __restrict__ w1t,   // [E][F][H] bf16 (B^T)
    const unsigned short* __restrict__ w3t,
    const int* __restrict__ ids,
    const int* __restrict__ cnt,
    const int* __restrict__ off,
    unsigned short* __restrict__ act)         // [8192][F] bf16
{
    const int e = blockIdx.z;
    const int cn = cnt[e];
    const int m0 = blockIdx.y * 128;
    if (m0 >= cn) return;
    const int n0 = blockIdx.x * 64;
    const int base = off[e];

    __shared__ __align__(16) unsigned short sA [128*64];  // 16 KB
    __shared__ __align__(16) unsigned short sB1[64*64];   // 8 KB
    __shared__ __align__(16) unsigned short sB3[64*64];   // 8 KB

    const int tid  = threadIdx.x;
    const int wid  = tid >> 6;
    const int lane = tid & 63;
    const int lrow = lane >> 3;          // 0..7: row within 8-row staging group
    const int lchk = lane & 7;           // chunk slot within row (8 x 16B = 128B row)

    // staging: chunk c of row stored at LDS slot c^(row&7)
    const unsigned short* aG[4];
    #pragma unroll
    for (int j = 0; j < 4; ++j) {
        const int row = (wid*4 + j)*8 + lrow;
        int rr = m0 + row; if (rr > cn - 1) rr = cn - 1;
        const int tok = ids[e*CAP + rr];
        const int c = lchk ^ (row & 7);
        aG[j] = xn + (size_t)tok*HID + c*8;
    }
    const unsigned short *b1G[2], *b3G[2];
    #pragma unroll
    for (int j = 0; j < 2; ++j) {
        const int row = (wid*2 + j)*8 + lrow;
        const int n = n0 + row;
        const int c = lchk ^ (row & 7);
        b1G[j] = w1t + ((size_t)e*FFN + n)*HID + c*8;
        b3G[j] = w3t + ((size_t)e*FFN + n)*HID + c*8;
    }

    floatx4 acc1[4][2], acc3[4][2];
    #pragma unroll
    for (int a = 0; a < 4; ++a)
      #pragma unroll
      for (int b = 0; b < 2; ++b) {
        acc1[a][b] = (floatx4){0.f,0.f,0.f,0.f};
        acc3[a][b] = (floatx4){0.f,0.f,0.f,0.f};
      }

    const int wm  = (wid >> 1) * 64;     // wave M offset
    const int wn  = (wid & 1) * 32;      // wave N offset
    const int r16 = lane & 15;
    const int q   = lane >> 4;
    const int rsw = r16 & 7;

    for (int kt = 0; kt < HID; kt += 64) {
        __syncthreads();
        #pragma unroll
        for (int j = 0; j < 4; ++j) GLOAD16(aG[j] + kt, sA + (wid*4 + j)*512);
        #pragma unroll
        for (int j = 0; j < 2; ++j) {
            GLOAD16(b1G[j] + kt, sB1 + (wid*2 + j)*512);
            GLOAD16(b3G[j] + kt, sB3 + (wid*2 + j)*512);
        }
        __syncthreads();
        #pragma unroll
        for (int kk = 0; kk < 2; ++kk) {
            const int slot = ((kk*4 + q) ^ rsw) << 3;   // un-swizzle on read
            bf16x8 a[4];
            #pragma unroll
            for (int mt = 0; mt < 4; ++mt)
                a[mt] = *(const bf16x8*)(sA + (wm + mt*16 + r16)*64 + slot);
            #pragma unroll
            for (int nt = 0; nt < 2; ++nt) {
                const bf16x8 b1 = *(const bf16x8*)(sB1 + (wn + nt*16 + r16)*64 + slot);
                const bf16x8 b3 = *(const bf16x8*)(sB3 + (wn + nt*16 + r16)*64 + slot);
                #pragma unroll
                for (int mt = 0; mt < 4; ++mt) {
                    acc1[mt][nt] = __builtin_amdgcn_mfma_f32_16x16x32_bf16(a[mt], b1, acc1[mt][nt], 0, 0, 0);
                    acc3[mt][nt] = __builtin_amdgcn_mfma_f32_16x16x32_bf16(a[mt], b3, acc3[mt][nt], 0, 0, 0);
                }
            }
        }
    }

    #pragma unroll
    for (int mt = 0; mt < 4; ++mt)
      #pragma unroll
      for (int i = 0; i < 4; ++i) {
        const int row = wm + mt*16 + q*4 + i;   // C/D: col=lane&15, row=(lane>>4)*4+reg
        if (m0 + row < cn) {
            unsigned short* rp = act + (size_t)(base + m0 + row)*FFN + n0 + wn + r16;
            #pragma unroll
            for (int nt = 0; nt < 2; ++nt) {
                const float h1 = acc1[mt][nt][i];
                const float h3 = acc3[mt][nt][i];
                rp[nt*16] = f2bf(h1 / (1.f + __expf(-h1)) * h3);
            }
        }
      }
}

// ---------------------------------------------------------------- GEMM2: out += gate * (act @ w2)
// Tile 128M x 64N x 64K. LDS 24 KB -> 4 blocks/CU. grid (n,m,e).
__global__ __launch_bounds__(256, 4) void k_gemm2(
    const unsigned short* __restrict__ act,
    const unsigned short* __restrict__ w2t,   // [E][H][F] bf16 (B^T)
    const int* __restrict__ ids,
    const float* __restrict__ gates,
    const int* __restrict__ cnt,
    const int* __restrict__ off,
    float* __restrict__ out)
{
    const int e = blockIdx.z;
    const int cn = cnt[e];
    const int m0 = blockIdx.y * 128;
    if (m0 >= cn) return;
    const int n0 = blockIdx.x * 64;
    const int base = off[e];

    __shared__ __align__(16) unsigned short sA[128*64];   // 16 KB
    __shared__ __align__(16) unsigned short sB[64*64];    // 8 KB

    const int tid  = threadIdx.x;
    const int wid  = tid >> 6;
    const int lane = tid & 63;
    const int lrow = lane >> 3;
    const int lchk = lane & 7;

    const unsigned short* aG[4];
    #pragma unroll
    for (int j = 0; j < 4; ++j) {
        const int row = (wid*4 + j)*8 + lrow;
        int rr = m0 + row; if (rr > cn - 1) rr = cn - 1;
        const int c = lchk ^ (row & 7);
        aG[j] = act + (size_t)(base + rr)*FFN + c*8;
    }
    const unsigned short* bG[2];
    #pragma unroll
    for (int j = 0; j < 2; ++j) {
        const int row = (wid*2 + j)*8 + lrow;
        const int c = lchk ^ (row & 7);
        bG[j] = w2t + ((size_t)e*HID + n0 + row)*FFN + c*8;
    }

    floatx4 acc[4][2];
    #pragma unroll
    for (int a = 0; a < 4; ++a)
      #pragma unroll
      for (int b = 0; b < 2; ++b) acc[a][b] = (floatx4){0.f,0.f,0.f,0.f};

    const int wm  = (wid >> 1) * 64;
    const int wn  = (wid & 1) * 32;
    const int r16 = lane & 15;
    const int q   = lane >> 4;
    const int rsw = r16 & 7;

    for (int kt = 0; kt < FFN; kt += 64) {
        __syncthreads();
        #pragma unroll
        for (int j = 0; j < 4; ++j) GLOAD16(aG[j] + kt, sA + (wid*4 + j)*512);
        #pragma unroll
        for (int j = 0; j < 2; ++j) GLOAD16(bG[j] + kt, sB + (wid*2 + j)*512);
        __syncthreads();
        #pragma unroll
        for (int kk = 0; kk < 2; ++kk) {
            const int slot = ((kk*4 + q) ^ rsw) << 3;
            bf16x8 a[4];
            #pragma unroll
            for (int mt = 0; mt < 4; ++mt)
                a[mt] = *(const bf16x8*)(sA + (wm + mt*16 + r16)*64 + slot);
            #pragma unroll
            for (int nt = 0; nt < 2; ++nt) {
                const bf16x8 b = *(const bf16x8*)(sB + (wn + nt*16 + r16)*64 + slot);
                #pragma unroll
                for (int mt = 0; mt < 4; ++mt)
                    acc[mt][nt] = __builtin_amdgcn_mfma_f32_16x16x32_bf16(a[mt], b, acc[mt][nt], 0, 0, 0);
            }
        }
    }

    #pragma unroll
    for (int mt = 0; mt < 4; ++mt)
      #pragma unroll
      for (int i = 0; i < 4; ++i) {
        const int row = wm + mt*16 + q*4 + i;
        if (m0 + row < cn) {
            const int idx = e*CAP + m0 + row;
            const int tok = ids[idx];
            const float gg = gates[idx];
            float* op = out + (size_t)tok*HID + n0 + wn + r16;
            #pragma unroll
            for (int nt = 0; nt < 2; ++nt)
                atomicAdd(op + nt*16, gg * acc[mt][nt][i]);
        }
      }
}

// ---------------------------------------------------------------- launch
extern "C" void kernel_launch(void* const* d_in, const int* in_sizes, int n_in,
                              void* d_out, int out_size, void* d_ws, size_t ws_size,
                              hipStream_t stream)
{
    const float* hs  = (const float*)d_in[0];
    const float* lnw = (const float*)d_in[1];
    const float* rw  = (const float*)d_in[2];
    const float* w1  = (const float*)d_in[3];
    const float* w3  = (const float*)d_in[4];
    const float* w2  = (const float*)d_in[5];
    float* out = (float*)d_out;
    char* ws = (char*)d_ws;

    constexpr size_t WS_CNT   = 0;
    constexpr size_t WS_OFF   = 64;
    constexpr size_t WS_IDS   = 256;
    constexpr size_t WS_GATES = WS_IDS + sizeof(int)*NE*CAP;          // 131328
    constexpr size_t WS_XN    = 327680;
    constexpr size_t WS_W1T   = WS_XN  + (size_t)2*TOKS*HID;          // +8 MiB
    constexpr size_t WS_W3T   = WS_W1T + (size_t)2*NE*FFN*HID;        // +44 MiB each
    constexpr size_t WS_W2T   = WS_W3T + (size_t)2*NE*FFN*HID;
    constexpr size_t WS_ACT   = WS_W2T + (size_t)2*NE*FFN*HID;
    constexpr size_t WS_END   = WS_ACT + (size_t)2*2*TOKS*FFN;        // ~184.3 MiB total

    hipMemsetAsync(out, 0, sizeof(float)*(size_t)out_size, stream);
    if (ws_size < WS_END) return;   // visible failure mode: zero output
    hipMemsetAsync(ws, 0, 256, stream);

    int* cnt   = (int*)(ws + WS_CNT);
    int* off   = (int*)(ws + WS_OFF);
    int* ids   = (int*)(ws + WS_IDS);
    float* gts = (float*)(ws + WS_GATES);
    unsigned short* xn  = (unsigned short*)(ws + WS_XN);
    unsigned short* w1t = (unsigned short*)(ws + WS_W1T);
    unsigned short* w3t = (unsigned short*)(ws + WS_W3T);
    unsigned short* w2t = (unsigned short*)(ws + WS_W2T);
    unsigned short* act = (unsigned short*)(ws + WS_ACT);

    k_rmsnorm  <<<TOKS,            256, 0, stream>>>(hs, lnw, xn);
    k_router   <<<TOKS/4,          256, 0, stream>>>(hs, lnw, rw, cnt, ids, gts);
    k_scan     <<<1,               64,  0, stream>>>(cnt, off);
    k_convtrans<<<dim3(704,3,NE),  256, 0, stream>>>(w1, w3, w2, w1t, w3t, w2t);
    k_gemm1    <<<dim3(44,32,NE),  256, 0, stream>>>(xn, w1t, w3t, ids, cnt, off, act);
    k_gemm2    <<<dim3(16,32,NE),  256, 0, stream>>>(act, w2t, ids, gts, cnt, off, out);
}

// Round 5
// 654.997 us; speedup vs baseline: 1.5561x; 1.1554x over previous
//
#include <hip/hip_runtime.h>
#include <cstdint>
#include <cstddef>

#define TOKS 4096
#define HID  1024
#define FFN  2816
#define NE   8
#define CAP  4096   // per-expert token capacity (power of 2 for slot packing)

using floatx4 = __attribute__((ext_vector_type(4))) float;
using bf16x8  = __attribute__((ext_vector_type(8))) short;

__device__ __forceinline__ unsigned short f2bf(float f) {
    union { float f; unsigned int u; } v; v.f = f;
    unsigned int r = v.u + 0x7FFFu + ((v.u >> 16) & 1u);   // RNE
    return (unsigned short)(r >> 16);
}

// async global->LDS, 16B per lane; LDS dest is wave-uniform base + lane*16
#define GLOAD16(g, l) __builtin_amdgcn_global_load_lds( \
    (__attribute__((address_space(1))) void*)(g),        \
    (__attribute__((address_space(3))) void*)(l), 16, 0, 0)

// ---------------------------------------------------------------- RMSNorm
__global__ __launch_bounds__(256) void k_rmsnorm(const float* __restrict__ x,
                                                 const float* __restrict__ g,
                                                 unsigned short* __restrict__ xn)
{
    const int t = blockIdx.x;
    const int tid = threadIdx.x;
    const float4 v = *(const float4*)(x + (size_t)t*HID + tid*4);
    float ss = v.x*v.x + v.y*v.y + v.z*v.z + v.w*v.w;
    #pragma unroll
    for (int s = 32; s; s >>= 1) ss += __shfl_xor(ss, s, 64);
    __shared__ float red[4];
    if ((tid & 63) == 0) red[tid >> 6] = ss;
    __syncthreads();
    const float tot = red[0] + red[1] + red[2] + red[3];
    const float sc = rsqrtf(tot * (1.0f/HID) + 1e-5f);
    const float4 gw = *(const float4*)(g + tid*4);
    ushort4 o;
    o.x = f2bf(v.x*sc*gw.x); o.y = f2bf(v.y*sc*gw.y);
    o.z = f2bf(v.z*sc*gw.z); o.w = f2bf(v.w*sc*gw.w);
    *(ushort4*)(xn + (size_t)t*HID + tid*4) = o;
}

// ---------------------------------------------------------------- Router (fp32, one wave per token)
__global__ __launch_bounds__(256) void k_router(const float* __restrict__ x,
                                                const float* __restrict__ g,
                                                const float* __restrict__ rw,  // [HID][NE]
                                                int* __restrict__ cnt,
                                                int* __restrict__ ids,
                                                float* __restrict__ gates,
                                                int* __restrict__ slot)        // [TOKS][2]
{
    const int wid = threadIdx.x >> 6, lane = threadIdx.x & 63;
    const int t = blockIdx.x*4 + wid;
    const float* xr = x + (size_t)t*HID;
    float ss = 0.f;
    float acc[NE];
    #pragma unroll
    for (int e = 0; e < NE; ++e) acc[e] = 0.f;
    for (int h = lane; h < HID; h += 64) {
        const float xv = xr[h];
        ss += xv*xv;
        const float xg = xv * g[h];
        const float4 r0 = *(const float4*)(rw + h*NE);
        const float4 r1 = *(const float4*)(rw + h*NE + 4);
        acc[0] += xg*r0.x; acc[1] += xg*r0.y; acc[2] += xg*r0.z; acc[3] += xg*r0.w;
        acc[4] += xg*r1.x; acc[5] += xg*r1.y; acc[6] += xg*r1.z; acc[7] += xg*r1.w;
    }
    #pragma unroll
    for (int s = 32; s; s >>= 1) {
        ss += __shfl_xor(ss, s, 64);
        #pragma unroll
        for (int e = 0; e < NE; ++e) acc[e] += __shfl_xor(acc[e], s, 64);
    }
    if (lane == 0) {
        const float sc = rsqrtf(ss * (1.0f/HID) + 1e-5f);
        float p[NE];
        float m = -1e30f;
        #pragma unroll
        for (int e = 0; e < NE; ++e) { p[e] = acc[e]*sc; if (p[e] > m) m = p[e]; }
        float sum = 0.f;
        #pragma unroll
        for (int e = 0; e < NE; ++e) { p[e] = __expf(p[e] - m); sum += p[e]; }
        const float inv = 1.f / sum;
        int i1 = 0; float p1 = p[0];
        #pragma unroll
        for (int e = 1; e < NE; ++e) if (p[e] > p1) { p1 = p[e]; i1 = e; }
        int i2 = -1; float p2 = -1.f;
        #pragma unroll
        for (int e = 0; e < NE; ++e) if (e != i1 && p[e] > p2) { p2 = p[e]; i2 = e; }
        int s0 = atomicAdd(cnt + i1, 1);
        ids[i1*CAP + s0] = t; gates[i1*CAP + s0] = p1*inv;
        slot[t*2 + 0] = i1*CAP + s0;
        int s1 = atomicAdd(cnt + i2, 1);
        ids[i2*CAP + s1] = t; gates[i2*CAP + s1] = p2*inv;
        slot[t*2 + 1] = i2*CAP + s1;
    }
}

// ---------------------------------------------------------------- prefix scan (8 experts)
__global__ void k_scan(const int* __restrict__ cnt, int* __restrict__ off)
{
    if (threadIdx.x == 0) {
        int s = 0;
        for (int e = 0; e < NE; ++e) { off[e] = s; s += cnt[e]; }
        off[NE] = s;
    }
}

// ---------------------------------------------------------------- fp32 -> bf16 transpose ([R][C] -> [C][R])
__global__ __launch_bounds__(256) void k_convtrans(const float* __restrict__ w1,
                                                   const float* __restrict__ w3,
                                                   const float* __restrict__ w2,
                                                   unsigned short* __restrict__ w1t,
                                                   unsigned short* __restrict__ w3t,
                                                   unsigned short* __restrict__ w2t)
{
    const int which = blockIdx.y;
    const int e = blockIdx.z;
    const float* src; unsigned short* dst; int R, C;
    if (which == 0)      { src = w1; dst = w1t; R = HID; C = FFN; }
    else if (which == 1) { src = w3; dst = w3t; R = HID; C = FFN; }
    else                 { src = w2; dst = w2t; R = FFN; C = HID; }
    src += (size_t)e * R * C;
    dst += (size_t)e * R * C;
    const int tiles_r = R >> 6;
    const int tr = blockIdx.x % tiles_r;
    const int tc = blockIdx.x / tiles_r;
    const int r0 = tr << 6, c0 = tc << 6;
    __shared__ unsigned short lds[64*66];
    const int tid = threadIdx.x;
    #pragma unroll
    for (int it = 0; it < 4; ++it) {
        const int id = it*256 + tid;
        const int r = id >> 4;
        const int c4 = (id & 15) << 2;
        const float4 v = *(const float4*)(src + (size_t)(r0 + r)*C + c0 + c4);
        lds[r*66 + c4 + 0] = f2bf(v.x);
        lds[r*66 + c4 + 1] = f2bf(v.y);
        lds[r*66 + c4 + 2] = f2bf(v.z);
        lds[r*66 + c4 + 3] = f2bf(v.w);
    }
    __syncthreads();
    #pragma unroll
    for (int it = 0; it < 2; ++it) {
        const int id = it*256 + tid;
        const int cc = id >> 3;           // 0..63
        const int rv = (id & 7) << 3;     // 0..56
        bf16x8 o;
        #pragma unroll
        for (int j = 0; j < 8; ++j) o[j] = (short)lds[(rv + j)*66 + cc];
        *(bf16x8*)(dst + (size_t)(c0 + cc)*R + r0 + rv) = o;
    }
}

// ---------------------------------------------------------------- GEMM1 (operand-swapped):
// D[f][t] = sum_h w1t[f][h] * xn[t][h]. Tile 128F x 64T x 64K. LDS 40 KB -> 4 blocks/CU.
__global__ __launch_bounds__(256, 4) void k_gemm1(
    const unsigned short* __restrict__ xn,
    const unsigned short* __restrict__ w1t,   // [E][F][H] bf16
    const unsigned short* __restrict__ w3t,
    const int* __restrict__ ids,
    const int* __restrict__ cnt,
    const int* __restrict__ off,
    unsigned short* __restrict__ act)         // [8192][F] bf16, compact token order
{
    const int e = blockIdx.z;
    const int cn = cnt[e];
    const int t0 = blockIdx.y * 64;
    if (t0 >= cn) return;
    const int f0 = blockIdx.x * 128;
    const int base = off[e];

    __shared__ __align__(16) unsigned short sA1[128*64];  // w1 tile, 16 KB
    __shared__ __align__(16) unsigned short sA3[128*64];  // w3 tile, 16 KB
    __shared__ __align__(16) unsigned short sB [64*64];   // x tile, 8 KB

    const int tid  = threadIdx.x;
    const int wid  = tid >> 6;
    const int lane = tid & 63;
    const int lrow = lane >> 3;          // 0..7
    const int lchk = lane & 7;

    // weight staging (A-side): 128 f-rows, 4 GLOAD16/wave each matrix
    const unsigned short *a1G[4], *a3G[4];
    #pragma unroll
    for (int j = 0; j < 4; ++j) {
        const int row = (wid*4 + j)*8 + lrow;
        const int c = lchk ^ (row & 7);
        a1G[j] = w1t + ((size_t)e*FFN + f0 + row)*HID + c*8;
        a3G[j] = w3t + ((size_t)e*FFN + f0 + row)*HID + c*8;
    }
    // token staging (B-side): 64 token-rows gathered via ids
    const unsigned short* bG[2];
    #pragma unroll
    for (int j = 0; j < 2; ++j) {
        const int row = (wid*2 + j)*8 + lrow;
        int rr = t0 + row; if (rr > cn - 1) rr = cn - 1;
        const int tok = ids[e*CAP + rr];
        const int c = lchk ^ (row & 7);
        bG[j] = xn + (size_t)tok*HID + c*8;
    }

    floatx4 acc1[4][2], acc3[4][2];
    #pragma unroll
    for (int a = 0; a < 4; ++a)
      #pragma unroll
      for (int b = 0; b < 2; ++b) {
        acc1[a][b] = (floatx4){0.f,0.f,0.f,0.f};
        acc3[a][b] = (floatx4){0.f,0.f,0.f,0.f};
      }

    const int wm  = (wid >> 1) * 64;     // wave F offset
    const int wn  = (wid & 1) * 32;      // wave T offset
    const int r16 = lane & 15;
    const int q   = lane >> 4;
    const int rsw = r16 & 7;

    for (int kt = 0; kt < HID; kt += 64) {
        __syncthreads();
        #pragma unroll
        for (int j = 0; j < 4; ++j) {
            GLOAD16(a1G[j] + kt, sA1 + (wid*4 + j)*512);
            GLOAD16(a3G[j] + kt, sA3 + (wid*4 + j)*512);
        }
        #pragma unroll
        for (int j = 0; j < 2; ++j) GLOAD16(bG[j] + kt, sB + (wid*2 + j)*512);
        __syncthreads();
        #pragma unroll
        for (int kk = 0; kk < 2; ++kk) {
            const int slot = ((kk*4 + q) ^ rsw) << 3;   // un-swizzle on read
            bf16x8 a1[4], a3[4];
            #pragma unroll
            for (int mt = 0; mt < 4; ++mt) {
                a1[mt] = *(const bf16x8*)(sA1 + (wm + mt*16 + r16)*64 + slot);
                a3[mt] = *(const bf16x8*)(sA3 + (wm + mt*16 + r16)*64 + slot);
            }
            #pragma unroll
            for (int nt = 0; nt < 2; ++nt) {
                const bf16x8 b = *(const bf16x8*)(sB + (wn + nt*16 + r16)*64 + slot);
                #pragma unroll
                for (int mt = 0; mt < 4; ++mt) {
                    acc1[mt][nt] = __builtin_amdgcn_mfma_f32_16x16x32_bf16(a1[mt], b, acc1[mt][nt], 0, 0, 0);
                    acc3[mt][nt] = __builtin_amdgcn_mfma_f32_16x16x32_bf16(a3[mt], b, acc3[mt][nt], 0, 0, 0);
                }
            }
        }
    }

    // D: col = lane&15 -> token, row = q*4+reg -> f (4 consecutive f per reg quad)
    #pragma unroll
    for (int nt = 0; nt < 2; ++nt) {
        const int t = t0 + wn + nt*16 + r16;
        if (t < cn) {
            unsigned short* rp = act + (size_t)(base + t)*FFN + f0;
            #pragma unroll
            for (int mt = 0; mt < 4; ++mt) {
                ushort4 o;
                float h1, h3;
                h1 = acc1[mt][nt][0]; h3 = acc3[mt][nt][0]; o.x = f2bf(h1/(1.f+__expf(-h1))*h3);
                h1 = acc1[mt][nt][1]; h3 = acc3[mt][nt][1]; o.y = f2bf(h1/(1.f+__expf(-h1))*h3);
                h1 = acc1[mt][nt][2]; h3 = acc3[mt][nt][2]; o.z = f2bf(h1/(1.f+__expf(-h1))*h3);
                h1 = acc1[mt][nt][3]; h3 = acc3[mt][nt][3]; o.w = f2bf(h1/(1.f+__expf(-h1))*h3);
                *(ushort4*)(rp + wm + mt*16 + q*4) = o;
            }
        }
    }
}

// ---------------------------------------------------------------- GEMM2 (operand-swapped):
// ytmp[t][h] = sum_f w2t[h][f] * act[t][f]. Tile 128H x 64T x 64K. LDS 24 KB.
__global__ __launch_bounds__(256, 4) void k_gemm2(
    const unsigned short* __restrict__ act,
    const unsigned short* __restrict__ w2t,   // [E][H][F] bf16
    const int* __restrict__ cnt,
    const int* __restrict__ off,
    float* __restrict__ ytmp)                 // [8192][H] fp32, compact token order
{
    const int e = blockIdx.z;
    const int cn = cnt[e];
    const int t0 = blockIdx.y * 64;
    if (t0 >= cn) return;
    const int h0 = blockIdx.x * 128;
    const int base = off[e];

    __shared__ __align__(16) unsigned short sA[128*64];   // w2 tile, 16 KB
    __shared__ __align__(16) unsigned short sB[64*64];    // act tile, 8 KB

    const int tid  = threadIdx.x;
    const int wid  = tid >> 6;
    const int lane = tid & 63;
    const int lrow = lane >> 3;
    const int lchk = lane & 7;

    const unsigned short* aG[4];
    #pragma unroll
    for (int j = 0; j < 4; ++j) {
        const int row = (wid*4 + j)*8 + lrow;
        const int c = lchk ^ (row & 7);
        aG[j] = w2t + ((size_t)e*HID + h0 + row)*FFN + c*8;
    }
    const unsigned short* bG[2];
    #pragma unroll
    for (int j = 0; j < 2; ++j) {
        const int row = (wid*2 + j)*8 + lrow;
        int rr = t0 + row; if (rr > cn - 1) rr = cn - 1;
        const int c = lchk ^ (row & 7);
        bG[j] = act + (size_t)(base + rr)*FFN + c*8;
    }

    floatx4 acc[4][2];
    #pragma unroll
    for (int a = 0; a < 4; ++a)
      #pragma unroll
      for (int b = 0; b < 2; ++b) acc[a][b] = (floatx4){0.f,0.f,0.f,0.f};

    const int wm  = (wid >> 1) * 64;     // wave H offset
    const int wn  = (wid & 1) * 32;      // wave T offset
    const int r16 = lane & 15;
    const int q   = lane >> 4;
    const int rsw = r16 & 7;

    for (int kt = 0; kt < FFN; kt += 64) {
        __syncthreads();
        #pragma unroll
        for (int j = 0; j < 4; ++j) GLOAD16(aG[j] + kt, sA + (wid*4 + j)*512);
        #pragma unroll
        for (int j = 0; j < 2; ++j) GLOAD16(bG[j] + kt, sB + (wid*2 + j)*512);
        __syncthreads();
        #pragma unroll
        for (int kk = 0; kk < 2; ++kk) {
            const int slot = ((kk*4 + q) ^ rsw) << 3;
            bf16x8 a[4];
            #pragma unroll
            for (int mt = 0; mt < 4; ++mt)
                a[mt] = *(const bf16x8*)(sA + (wm + mt*16 + r16)*64 + slot);
            #pragma unroll
            for (int nt = 0; nt < 2; ++nt) {
                const bf16x8 b = *(const bf16x8*)(sB + (wn + nt*16 + r16)*64 + slot);
                #pragma unroll
                for (int mt = 0; mt < 4; ++mt)
                    acc[mt][nt] = __builtin_amdgcn_mfma_f32_16x16x32_bf16(a[mt], b, acc[mt][nt], 0, 0, 0);
            }
        }
    }

    // D: col -> token, reg quad -> 4 consecutive h. float4 store per (mt,nt).
    #pragma unroll
    for (int nt = 0; nt < 2; ++nt) {
        const int t = t0 + wn + nt*16 + r16;
        if (t < cn) {
            float* rp = ytmp + (size_t)(base + t)*HID + h0;
            #pragma unroll
            for (int mt = 0; mt < 4; ++mt) {
                float4 o = { acc[mt][nt][0], acc[mt][nt][1], acc[mt][nt][2], acc[mt][nt][3] };
                *(float4*)(rp + wm + mt*16 + q*4) = o;
            }
        }
    }
}

// ---------------------------------------------------------------- Combine: out = g0*y[c0] + g1*y[c1]
__global__ __launch_bounds__(256) void k_combine(const float* __restrict__ ytmp,
                                                 const int* __restrict__ slot,
                                                 const float* __restrict__ gates,
                                                 const int* __restrict__ off,
                                                 float* __restrict__ out)
{
    const int t = blockIdx.x;
    const int tid = threadIdx.x;
    const int s0 = slot[t*2 + 0], s1 = slot[t*2 + 1];
    const float g0 = gates[s0],    g1 = gates[s1];
    const int c0 = off[s0 >> 12] + (s0 & (CAP-1));
    const int c1 = off[s1 >> 12] + (s1 & (CAP-1));
    const float4 y0 = *(const float4*)(ytmp + (size_t)c0*HID + tid*4);
    const float4 y1 = *(const float4*)(ytmp + (size_t)c1*HID + tid*4);
    float4 o;
    o.x = g0*y0.x + g1*y1.x;
    o.y = g0*y0.y + g1*y1.y;
    o.z = g0*y0.z + g1*y1.z;
    o.w = g0*y0.w + g1*y1.w;
    *(float4*)(out + (size_t)t*HID + tid*4) = o;
}

// ---------------------------------------------------------------- launch
extern "C" void kernel_launch(void* const* d_in, const int* in_sizes, int n_in,
                              void* d_out, int out_size, void* d_ws, size_t ws_size,
                              hipStream_t stream)
{
    const float* hs  = (const float*)d_in[0];
    const float* lnw = (const float*)d_in[1];
    const float* rw  = (const float*)d_in[2];
    const float* w1  = (const float*)d_in[3];
    const float* w3  = (const float*)d_in[4];
    const float* w2  = (const float*)d_in[5];
    float* out = (float*)d_out;
    char* ws = (char*)d_ws;

    constexpr size_t WS_CNT   = 0;
    constexpr size_t WS_OFF   = 64;
    constexpr size_t WS_IDS   = 256;
    constexpr size_t WS_GATES = WS_IDS + sizeof(int)*NE*CAP;          // 131328
    constexpr size_t WS_SLOT  = WS_GATES + sizeof(float)*NE*CAP;      // 262400
    constexpr size_t WS_XN    = 327680;
    constexpr size_t WS_W1T   = WS_XN  + (size_t)2*TOKS*HID;          // +8 MiB
    constexpr size_t WS_W3T   = WS_W1T + (size_t)2*NE*FFN*HID;        // +44 MiB each
    constexpr size_t WS_W2T   = WS_W3T + (size_t)2*NE*FFN*HID;
    constexpr size_t WS_ACT   = WS_W2T + (size_t)2*NE*FFN*HID;
    constexpr size_t WS_END   = WS_ACT + (size_t)2*2*TOKS*FFN;        // ~184.3 MiB total
    // ytmp (32 MiB fp32) aliases the w1t region: w1t is dead once gemm1 completes,
    // and the stream serializes gemm1 -> gemm2 -> combine.

    if (ws_size < WS_END) { hipMemsetAsync(out, 0, sizeof(float)*(size_t)out_size, stream); return; }
    hipMemsetAsync(ws, 0, 256, stream);

    int* cnt   = (int*)(ws + WS_CNT);
    int* off   = (int*)(ws + WS_OFF);
    int* ids   = (int*)(ws + WS_IDS);
    float* gts = (float*)(ws + WS_GATES);
    int* slot  = (int*)(ws + WS_SLOT);
    unsigned short* xn  = (unsigned short*)(ws + WS_XN);
    unsigned short* w1t = (unsigned short*)(ws + WS_W1T);
    unsigned short* w3t = (unsigned short*)(ws + WS_W3T);
    unsigned short* w2t = (unsigned short*)(ws + WS_W2T);
    unsigned short* act = (unsigned short*)(ws + WS_ACT);
    float* ytmp = (float*)(ws + WS_W1T);   // alias, see note above

    k_rmsnorm  <<<TOKS,            256, 0, stream>>>(hs, lnw, xn);
    k_router   <<<TOKS/4,          256, 0, stream>>>(hs, lnw, rw, cnt, ids, gts, slot);
    k_scan     <<<1,               64,  0, stream>>>(cnt, off);
    k_convtrans<<<dim3(704,3,NE),  256, 0, stream>>>(w1, w3, w2, w1t, w3t, w2t);
    k_gemm1    <<<dim3(22,64,NE),  256, 0, stream>>>(xn, w1t, w3t, ids, cnt, off, act);
    k_gemm2    <<<dim3(8,64,NE),   256, 0, stream>>>(act, w2t, cnt, off, ytmp);
    k_combine  <<<TOKS,            256, 0, stream>>>(ytmp, slot, gts, off, out);
}